// Round 4
// baseline (383.361 us; speedup 1.0000x reference)
//
#include <hip/hip_runtime.h>
#include <math.h>

typedef short  short8  __attribute__((ext_vector_type(8)));
typedef float  floatx4 __attribute__((ext_vector_type(4)));

#define NROWS 16384
#define KC    2048
#define DIM   512
#define MB    32      // rows per k_main block

// d_out element offsets (all float32): loss, q[8388608], perplexity, idx[16384]
#define OUT_Q_OFF    1
#define OUT_P_OFF    (1 + 8388608)
#define OUT_IDX_OFF  (1 + 8388608 + 1)

// ws byte offsets
#define WS_COUNTS 0        // int[2048]   (zeroed each call)
#define WS_LOSS   8192     // float       (zeroed each call)
#define WS_W2D    8448     // double[2048]
#define WS_W2F    24832    // float[2048]
#define WS_WB     33024    // ushort[2048*512] bf16 codebook, FRAGMENT-ORDERED (2 MB)

__device__ __forceinline__ unsigned short f2bf(float f) {
  union { float f; unsigned int u; } v; v.f = f;
  unsigned int u = v.u;
  return (unsigned short)((u + 0x7fffu + ((u >> 16) & 1u)) >> 16);
}

// monotone pack: fp32 score -> ascending uint, low 11 bits replaced by code
__device__ __forceinline__ unsigned int packsc(float s, int code) {
  union { float f; unsigned int u; } v; v.f = s;
  unsigned int u = v.u;
  u = (u & 0x80000000u) ? ~u : (u | 0x80000000u);
  return (u & 0xFFFFF800u) | (unsigned int)code;
}

__device__ __forceinline__ void ins3(unsigned int* t, unsigned int v) {
  if (v < t[2]) {
    t[2] = v;
    if (t[2] < t[1]) { unsigned int tmp = t[1]; t[1] = t[2]; t[2] = tmp; }
    if (t[1] < t[0]) { unsigned int tmp = t[0]; t[0] = t[1]; t[1] = tmp; }
  }
}

// ---------------- k_w2: ||W_k||^2 in fp64 + fp32
__global__ __launch_bounds__(256) void k_w2(const float* __restrict__ W,
                                            double* __restrict__ w2d,
                                            float* __restrict__ w2f) {
  int wave = threadIdx.x >> 6;
  int lane = threadIdx.x & 63;
  int k = blockIdx.x * 4 + wave;
  const float4* row = (const float4*)(W + (size_t)k * DIM);
  float4 a = row[lane];
  float4 b = row[lane + 64];
  double acc = 0.0;
  acc += (double)a.x*a.x + (double)a.y*a.y + (double)a.z*a.z + (double)a.w*a.w;
  acc += (double)b.x*b.x + (double)b.y*b.y + (double)b.z*b.z + (double)b.w*b.w;
  for (int o = 32; o > 0; o >>= 1) acc += __shfl_down(acc, o);
  if (lane == 0) { w2d[k] = acc; w2f[k] = (float)acc; }
}

// ---------------- k_reorder: W -> bf16 codebook in MFMA B-fragment order.
__global__ __launch_bounds__(256) void k_reorder(const float* __restrict__ W,
                                                 unsigned short* __restrict__ Wb) {
  int gid  = blockIdx.x * 256 + threadIdx.x;   // 131072 total
  int lane = gid & 63;
  int f    = gid >> 6;                          // 0..2047
  int c16  = f >> 4, ks = f & 15;
  int l15  = lane & 15, q = lane >> 4;
  const float* src = W + (size_t)(c16 * 16 + l15) * DIM + ks * 32 + q * 8;
  float4 a = *(const float4*)src;
  float4 b = *(const float4*)(src + 4);
  short8 v;
  v[0] = (short)f2bf(a.x); v[1] = (short)f2bf(a.y);
  v[2] = (short)f2bf(a.z); v[3] = (short)f2bf(a.w);
  v[4] = (short)f2bf(b.x); v[5] = (short)f2bf(b.y);
  v[6] = (short)f2bf(b.z); v[7] = (short)f2bf(b.w);
  *(short8*)(Wb + (size_t)f * 512 + lane * 8) = v;
}

// ---------------- k_main: barrier-free bf16 MFMA streaming -> top-8 -> fp64
//                  refine -> idx/counts + fused quantize/loss epilogue.
// All streaming traffic (x, W gathers, out) is NON-TEMPORAL so the 2 MB Wb
// B-stream stays L2-resident (the round-3 bottleneck was Wb evicted to L3).
__global__ __launch_bounds__(256, 2) void k_main(
    const float* __restrict__ x, const float* __restrict__ W,
    const unsigned short* __restrict__ Wb,
    const float* __restrict__ w2f, const double* __restrict__ w2d,
    int* __restrict__ counts, float* __restrict__ out,
    float* __restrict__ loss_acc)
{
  __shared__ unsigned int candU[MB * 192];   // 24 KB packed candidates
  __shared__ unsigned int ps8[MB][8][8];     // 8 KB partial top-8
  __shared__ int    top8i[MB][8];
  __shared__ double sc8[MB][8];
  __shared__ int4   idx3s[MB];
  __shared__ float  lred[4];

  const int tid  = threadIdx.x;
  const int w    = tid >> 6;          // wave id: owns codes [w*512, w*512+512)
  const int lane = tid & 63;
  const int q    = lane >> 4;
  const int l15  = lane & 15;
  const int n0   = blockIdx.x * MB;
  const int b    = n0 >> 8;
  const int t0   = n0 & 255;

  // ---- Phase A: 32 rows -> bf16 A-fragments in registers (nt loads)
  short8 af[2][16];
  {
    const float* xp = x + (size_t)b * DIM * 256 + t0 + l15;
    #pragma unroll
    for (int rs = 0; rs < 2; ++rs)
      #pragma unroll
      for (int s = 0; s < 16; ++s) {
        short8 v;
        #pragma unroll
        for (int j = 0; j < 8; ++j) {
          int d = s * 32 + q * 8 + j;
          v[j] = (short)f2bf(__builtin_nontemporal_load(
                     &xp[(size_t)d * 256 + rs * 16]));
        }
        af[rs][s] = v;
      }
  }

  unsigned int ts[2][4][3];   // packed top-3 per (rowset, acc-reg)
  #pragma unroll
  for (int rs = 0; rs < 2; ++rs)
    #pragma unroll
    for (int i = 0; i < 4; ++i)
      #pragma unroll
      for (int j = 0; j < 3; ++j) ts[rs][i][j] = 0xFFFFFFFFu;

  // ---- Phase B: barrier-free GEMM. Each wave streams its 512 KB of
  //      fragment-ordered Wb (L2-resident) through an 8-deep register ring.
  {
    const unsigned short* base = Wb + (size_t)(w * 512) * 512 + lane * 8;
    short8 ring[8];
    #pragma unroll
    for (int p = 0; p < 8; ++p)
      ring[p] = *(const short8*)(base + (size_t)p * 512);

    for (int ct = 0; ct < 32; ++ct) {
      floatx4 acc0 = {0.f, 0.f, 0.f, 0.f};
      floatx4 acc1 = {0.f, 0.f, 0.f, 0.f};
      #pragma unroll
      for (int ks = 0; ks < 16; ++ks) {
        int it = ct * 16 + ks;
        int nf = (it + 8 < 512) ? (it + 8) : 511;   // wave-uniform clamp
        short8 bfr = ring[ks & 7];
        ring[ks & 7] = *(const short8*)(base + (size_t)nf * 512);
        acc0 = __builtin_amdgcn_mfma_f32_16x16x32_bf16(af[0][ks], bfr, acc0, 0, 0, 0);
        acc1 = __builtin_amdgcn_mfma_f32_16x16x32_bf16(af[1][ks], bfr, acc1, 0, 0, 0);
      }
      int code = (w * 32 + ct) * 16 + l15;
      float w2 = w2f[code];
      #pragma unroll
      for (int i = 0; i < 4; ++i) {
        ins3(ts[0][i], packsc(fmaf(-2.0f, acc0[i], w2), code));
        ins3(ts[1][i], packsc(fmaf(-2.0f, acc1[i], w2), code));
      }
    }
  }

  // ---- Phase C: dump packed candidates, two-stage merge -> top-8 per row
  #pragma unroll
  for (int rs = 0; rs < 2; ++rs)
    #pragma unroll
    for (int i = 0; i < 4; ++i) {
      int row = rs * 16 + q * 4 + i;
      #pragma unroll
      for (int j = 0; j < 3; ++j)
        candU[row * 192 + w * 48 + l15 * 3 + j] = ts[rs][i][j];
    }
  __syncthreads();

  {
    int row = tid >> 3, sl = tid & 7;
    unsigned int s8[8];
    #pragma unroll
    for (int k = 0; k < 8; ++k) s8[k] = 0xFFFFFFFFu;
    for (int e = 0; e < 24; ++e) {
      unsigned int v = candU[row * 192 + sl * 24 + e];
      if (v < s8[7]) {
        s8[7] = v;
        #pragma unroll
        for (int k = 7; k >= 1; --k)
          if (s8[k] < s8[k - 1]) { unsigned int t = s8[k-1]; s8[k-1] = s8[k]; s8[k] = t; }
      }
    }
    #pragma unroll
    for (int k = 0; k < 8; ++k) ps8[row][sl][k] = s8[k];
  }
  __syncthreads();

  if (tid < MB) {
    unsigned int s8[8];
    #pragma unroll
    for (int k = 0; k < 8; ++k) s8[k] = 0xFFFFFFFFu;
    const unsigned int* src = &ps8[tid][0][0];
    for (int e = 0; e < 64; ++e) {
      unsigned int v = src[e];
      if (v < s8[7]) {
        s8[7] = v;
        #pragma unroll
        for (int k = 7; k >= 1; --k)
          if (s8[k] < s8[k - 1]) { unsigned int t = s8[k-1]; s8[k-1] = s8[k]; s8[k] = t; }
      }
    }
    #pragma unroll
    for (int k = 0; k < 8; ++k) top8i[tid][k] = (int)(s8[k] & 0x7FFu);
  }
  __syncthreads();

  // ---- Phase D: exact fp64 re-score of 8 candidates per row (nt loads)
  {
    int rr = tid >> 3, j = tid & 7;
    int code = top8i[rr][j];
    const floatx4* wr4 = (const floatx4*)(W + (size_t)code * DIM);
    const float*   xr  = x + (size_t)b * DIM * 256 + t0 + rr;
    double d0 = 0.0, d1 = 0.0, d2 = 0.0, d3 = 0.0;
    for (int d4 = 0; d4 < 128; ++d4) {
      floatx4 wv = __builtin_nontemporal_load(wr4 + d4);
      float xa = __builtin_nontemporal_load(&xr[(size_t)(d4*4 + 0) * 256]);
      float xb = __builtin_nontemporal_load(&xr[(size_t)(d4*4 + 1) * 256]);
      float xc = __builtin_nontemporal_load(&xr[(size_t)(d4*4 + 2) * 256]);
      float xd = __builtin_nontemporal_load(&xr[(size_t)(d4*4 + 3) * 256]);
      d0 = fma((double)xa, (double)wv[0], d0);
      d1 = fma((double)xb, (double)wv[1], d1);
      d2 = fma((double)xc, (double)wv[2], d2);
      d3 = fma((double)xd, (double)wv[3], d3);
    }
    sc8[rr][j] = w2d[code] - 2.0 * ((d0 + d1) + (d2 + d3));
  }
  __syncthreads();

  // ---- final order: sort 8 by (score, index) asc == top_k(-dist) order
  if (tid < MB) {
    double sd[8]; int id_[8];
    #pragma unroll
    for (int k = 0; k < 8; ++k) { sd[k] = sc8[tid][k]; id_[k] = top8i[tid][k]; }
    #pragma unroll
    for (int i = 0; i < 7; ++i)
      #pragma unroll
      for (int jj = 0; jj < 7; ++jj)
        if (jj < 7 - i) {
          bool sw = (sd[jj] > sd[jj+1]) ||
                    (sd[jj] == sd[jj+1] && id_[jj] > id_[jj+1]);
          if (sw) {
            double td = sd[jj]; sd[jj] = sd[jj+1]; sd[jj+1] = td;
            int    tt = id_[jj]; id_[jj] = id_[jj+1]; id_[jj+1] = tt;
          }
        }
    int n = n0 + tid;
    idx3s[tid] = make_int4(id_[0], id_[1], id_[2], 0);
    __builtin_nontemporal_store((float)id_[2], &out[OUT_IDX_OFF + n]);
    atomicAdd(&counts[id_[0]], 1);
    atomicAdd(&counts[id_[1]], 1);
    atomicAdd(&counts[id_[2]], 1);
  }
  __syncthreads();

  // ---- Phase E: fused quantize + straight-through + loss (nt everywhere)
  {
    int rr = tid & 31, g = tid >> 5;       // 8 d-groups of 64 dims
    int4 ii = idx3s[rr];
    const floatx4* w0 = (const floatx4*)(W + (size_t)ii.x * DIM);
    const floatx4* w1 = (const floatx4*)(W + (size_t)ii.y * DIM);
    const floatx4* w2 = (const floatx4*)(W + (size_t)ii.z * DIM);
    const float*   xr = x + (size_t)b * DIM * 256 + t0 + rr;
    float* outq = out + OUT_Q_OFF + (size_t)b * DIM * 256 + t0 + rr;
    float lsum = 0.0f;
    #pragma unroll 4
    for (int d4 = 0; d4 < 16; ++d4) {
      int idx4 = g * 16 + d4;
      floatx4 a0 = __builtin_nontemporal_load(w0 + idx4);
      floatx4 a1 = __builtin_nontemporal_load(w1 + idx4);
      floatx4 a2 = __builtin_nontemporal_load(w2 + idx4);
      #pragma unroll
      for (int e = 0; e < 4; ++e) {
        float qv = (a0[e] + a1[e] + a2[e]) * (1.0f / 3.0f);
        size_t off = (size_t)(idx4 * 4 + e) * 256;
        float xv = __builtin_nontemporal_load(&xr[off]);
        float diff = qv - xv;                          // quantized - inp
        __builtin_nontemporal_store(xv + diff, &outq[off]);
        lsum += diff * diff;
      }
    }
    for (int o = 32; o > 0; o >>= 1) lsum += __shfl_down(lsum, o);
    if (lane == 0) lred[w] = lsum;
  }
  __syncthreads();
  if (tid == 0)
    atomicAdd(loss_acc, (lred[0] + lred[1]) + (lred[2] + lred[3]));
}

// ---------------- k_final: loss + perplexity
__global__ __launch_bounds__(256) void k_final(
    const int* __restrict__ counts, const float* __restrict__ loss_acc,
    float* __restrict__ out)
{
  int tid = threadIdx.x;
  float ent = 0.0f;
  for (int k = tid; k < KC; k += 256) {
    float p = (float)counts[k] * (1.0f / 16384.0f);
    ent += p * logf(p + 1e-10f);
  }
  for (int o = 32; o > 0; o >>= 1) ent += __shfl_down(ent, o);
  __shared__ float ps[4];
  if ((tid & 63) == 0) ps[tid >> 6] = ent;
  __syncthreads();
  if (tid == 0) {
    float total = (ps[0] + ps[1]) + (ps[2] + ps[3]);
    out[0] = 1.25f * loss_acc[0] * (1.0f / 8388608.0f);  // q + 0.25*e latent
    out[OUT_P_OFF] = expf(-total);
  }
}

extern "C" void kernel_launch(void* const* d_in, const int* in_sizes, int n_in,
                              void* d_out, int out_size, void* d_ws, size_t ws_size,
                              hipStream_t stream) {
  const float* x = (const float*)d_in[0];
  const float* W = (const float*)d_in[1];
  float* out = (float*)d_out;
  char* ws = (char*)d_ws;
  int*            counts   = (int*)(ws + WS_COUNTS);
  float*          loss_acc = (float*)(ws + WS_LOSS);
  double*         w2d      = (double*)(ws + WS_W2D);
  float*          w2f      = (float*)(ws + WS_W2F);
  unsigned short* Wb       = (unsigned short*)(ws + WS_WB);

  hipMemsetAsync(ws, 0, 8448, stream);   // counts + loss accumulator
  k_w2<<<KC / 4, 256, 0, stream>>>(W, w2d, w2f);
  k_reorder<<<512, 256, 0, stream>>>(W, Wb);
  k_main<<<NROWS / MB, 256, 0, stream>>>(x, W, Wb, w2f, w2d, counts, out, loss_acc);
  k_final<<<1, 256, 0, stream>>>(counts, loss_acc, out);
}

// Round 5
// 237.721 us; speedup vs baseline: 1.6126x; 1.6126x over previous
//
#include <hip/hip_runtime.h>
#include <math.h>

typedef float     floatx4 __attribute__((ext_vector_type(4)));
typedef long long i64;

#define NROWS 16384
#define KC    2048
#define DIM   512
#define MB    32      // rows per k_main block

// d_out element offsets (all float32): loss, q[8388608], perplexity, idx[16384]
#define OUT_Q_OFF    1
#define OUT_P_OFF    (1 + 8388608)
#define OUT_IDX_OFF  (1 + 8388608 + 1)

// ws byte offsets
#define WS_COUNTS 0        // int[2048]   (zeroed each call)
#define WS_LOSS   8192     // float       (zeroed each call)
#define WS_W2D    8448     // double[2048]
#define WS_W2F    24832    // float[2048]
#define WS_WB     33024    // uchar[2048*512] fp8 codebook (W*2048), FRAG-ORDERED, 1 MB

// pack 8 floats -> 8 fp8 e4m3 bytes (RNE, saturating)
__device__ __forceinline__ i64 pk_fp8x8(float f0, float f1, float f2, float f3,
                                        float f4, float f5, float f6, float f7) {
  int lo = __builtin_amdgcn_cvt_pk_fp8_f32(f0, f1, 0, false);
  lo     = __builtin_amdgcn_cvt_pk_fp8_f32(f2, f3, lo, true);
  int hi = __builtin_amdgcn_cvt_pk_fp8_f32(f4, f5, 0, false);
  hi     = __builtin_amdgcn_cvt_pk_fp8_f32(f6, f7, hi, true);
  return (i64)(((unsigned long long)(unsigned int)hi << 32) | (unsigned int)lo);
}

// monotone pack: fp32 score -> ascending uint, low 11 bits replaced by code
__device__ __forceinline__ unsigned int packsc(float s, int code) {
  union { float f; unsigned int u; } v; v.f = s;
  unsigned int u = v.u;
  u = (u & 0x80000000u) ? ~u : (u | 0x80000000u);
  return (u & 0xFFFFF800u) | (unsigned int)code;
}

__device__ __forceinline__ void ins3(unsigned int* t, unsigned int v) {
  if (v < t[2]) {
    t[2] = v;
    if (t[2] < t[1]) { unsigned int tmp = t[1]; t[1] = t[2]; t[2] = tmp; }
    if (t[1] < t[0]) { unsigned int tmp = t[0]; t[0] = t[1]; t[1] = tmp; }
  }
}

// ---------------- k_w2: ||W_k||^2 in fp64 + fp32
__global__ __launch_bounds__(256) void k_w2(const float* __restrict__ W,
                                            double* __restrict__ w2d,
                                            float* __restrict__ w2f) {
  int wave = threadIdx.x >> 6;
  int lane = threadIdx.x & 63;
  int k = blockIdx.x * 4 + wave;
  const float4* row = (const float4*)(W + (size_t)k * DIM);
  float4 a = row[lane];
  float4 b = row[lane + 64];
  double acc = 0.0;
  acc += (double)a.x*a.x + (double)a.y*a.y + (double)a.z*a.z + (double)a.w*a.w;
  acc += (double)b.x*b.x + (double)b.y*b.y + (double)b.z*b.z + (double)b.w*b.w;
  for (int o = 32; o > 0; o >>= 1) acc += __shfl_down(acc, o);
  if (lane == 0) { w2d[k] = acc; w2f[k] = (float)acc; }
}

// ---------------- k_reorder: W -> fp8 codebook (scaled by 2048) in MFMA
// B-fragment order. frag f = c16*16 + ks (c16: 16-code tile, ks: K=32 step),
// 512 B each. lane (q,l15) holds W[c16*16+l15][ks*32+q*8 .. +8) * 2048.
__global__ __launch_bounds__(256) void k_reorder(const float* __restrict__ W,
                                                 unsigned char* __restrict__ Wb) {
  int gid  = blockIdx.x * 256 + threadIdx.x;   // 131072 total
  int lane = gid & 63;
  int f    = gid >> 6;                          // 0..2047
  int c16  = f >> 4, ks = f & 15;
  int l15  = lane & 15, q = lane >> 4;
  const float* src = W + (size_t)(c16 * 16 + l15) * DIM + ks * 32 + q * 8;
  float4 a = *(const float4*)src;
  float4 b = *(const float4*)(src + 4);
  i64 v = pk_fp8x8(a.x * 2048.0f, a.y * 2048.0f, a.z * 2048.0f, a.w * 2048.0f,
                   b.x * 2048.0f, b.y * 2048.0f, b.z * 2048.0f, b.w * 2048.0f);
  *(i64*)(Wb + (size_t)f * 512 + lane * 8) = v;
}

// ---------------- k_main: barrier-free fp8 MFMA streaming -> top-8 -> fp64
//                  refine -> idx/counts + fused quantize/loss epilogue
__global__ __launch_bounds__(256, 2) void k_main(
    const float* __restrict__ x, const float* __restrict__ W,
    const unsigned char* __restrict__ Wb,
    const float* __restrict__ w2f, const double* __restrict__ w2d,
    int* __restrict__ counts, float* __restrict__ out,
    float* __restrict__ loss_acc)
{
  __shared__ unsigned int candU[MB * 192];   // 24 KB packed candidates
  __shared__ unsigned int ps8[MB][8][8];     // 8 KB partial top-8
  __shared__ int    top8i[MB][8];
  __shared__ double sc8[MB][8];
  __shared__ int4   idx3s[MB];
  __shared__ float  lred[4];

  const int tid  = threadIdx.x;
  const int w    = tid >> 6;          // wave id: owns codes [w*512, w*512+512)
  const int lane = tid & 63;
  const int q    = lane >> 4;
  const int l15  = lane & 15;
  const int n0   = blockIdx.x * MB;
  const int b    = n0 >> 8;
  const int t0   = n0 & 255;

  // ---- Phase A: 32 rows -> fp8 A-fragments in registers (2 rowsets x 16 ksteps)
  i64 af[2][16];
  {
    const float* xp = x + (size_t)b * DIM * 256 + t0 + l15;
    #pragma unroll
    for (int rs = 0; rs < 2; ++rs)
      #pragma unroll
      for (int s = 0; s < 16; ++s) {
        float f[8];
        #pragma unroll
        for (int j = 0; j < 8; ++j) {
          int d = s * 32 + q * 8 + j;
          f[j] = xp[(size_t)d * 256 + rs * 16];
        }
        af[rs][s] = pk_fp8x8(f[0], f[1], f[2], f[3], f[4], f[5], f[6], f[7]);
      }
  }

  unsigned int ts[2][4][3];   // packed top-3 per (rowset, acc-reg)
  #pragma unroll
  for (int rs = 0; rs < 2; ++rs)
    #pragma unroll
    for (int i = 0; i < 4; ++i)
      #pragma unroll
      for (int j = 0; j < 3; ++j) ts[rs][i][j] = 0xFFFFFFFFu;

  // ---- Phase B: barrier-free GEMM. Each wave streams its 256 KB of
  //      fragment-ordered fp8 Wb through an 8-deep register ring.
  {
    const unsigned char* base = Wb + (size_t)(w * 512) * 512 + lane * 8;
    i64 ring[8];
    #pragma unroll
    for (int p = 0; p < 8; ++p)
      ring[p] = *(const i64*)(base + (size_t)p * 512);

    for (int ct = 0; ct < 32; ++ct) {
      floatx4 acc0 = {0.f, 0.f, 0.f, 0.f};
      floatx4 acc1 = {0.f, 0.f, 0.f, 0.f};
      #pragma unroll
      for (int ks = 0; ks < 16; ++ks) {
        int it = ct * 16 + ks;
        int nf = (it + 8 < 512) ? (it + 8) : 511;   // wave-uniform clamp
        i64 bfr = ring[ks & 7];
        ring[ks & 7] = *(const i64*)(base + (size_t)nf * 512);
        acc0 = __builtin_amdgcn_mfma_f32_16x16x32_fp8_fp8(af[0][ks], bfr, acc0, 0, 0, 0);
        acc1 = __builtin_amdgcn_mfma_f32_16x16x32_fp8_fp8(af[1][ks], bfr, acc1, 0, 0, 0);
      }
      // acc = 2048 * dot  =>  s = w2 - 2*dot = fma(-2/2048, acc, w2)
      int code = (w * 32 + ct) * 16 + l15;
      float w2 = w2f[code];
      #pragma unroll
      for (int i = 0; i < 4; ++i) {
        ins3(ts[0][i], packsc(fmaf(-0.0009765625f, acc0[i], w2), code));
        ins3(ts[1][i], packsc(fmaf(-0.0009765625f, acc1[i], w2), code));
      }
    }
  }

  // ---- Phase C: dump packed candidates, two-stage merge -> top-8 per row
  #pragma unroll
  for (int rs = 0; rs < 2; ++rs)
    #pragma unroll
    for (int i = 0; i < 4; ++i) {
      int row = rs * 16 + q * 4 + i;
      #pragma unroll
      for (int j = 0; j < 3; ++j)
        candU[row * 192 + w * 48 + l15 * 3 + j] = ts[rs][i][j];
    }
  __syncthreads();

  {
    int row = tid >> 3, sl = tid & 7;
    unsigned int s8[8];
    #pragma unroll
    for (int k = 0; k < 8; ++k) s8[k] = 0xFFFFFFFFu;
    for (int e = 0; e < 24; ++e) {
      unsigned int v = candU[row * 192 + sl * 24 + e];
      if (v < s8[7]) {
        s8[7] = v;
        #pragma unroll
        for (int k = 7; k >= 1; --k)
          if (s8[k] < s8[k - 1]) { unsigned int t = s8[k-1]; s8[k-1] = s8[k]; s8[k] = t; }
      }
    }
    #pragma unroll
    for (int k = 0; k < 8; ++k) ps8[row][sl][k] = s8[k];
  }
  __syncthreads();

  if (tid < MB) {
    unsigned int s8[8];
    #pragma unroll
    for (int k = 0; k < 8; ++k) s8[k] = 0xFFFFFFFFu;
    const unsigned int* src = &ps8[tid][0][0];
    for (int e = 0; e < 64; ++e) {
      unsigned int v = src[e];
      if (v < s8[7]) {
        s8[7] = v;
        #pragma unroll
        for (int k = 7; k >= 1; --k)
          if (s8[k] < s8[k - 1]) { unsigned int t = s8[k-1]; s8[k-1] = s8[k]; s8[k] = t; }
      }
    }
    #pragma unroll
    for (int k = 0; k < 8; ++k) top8i[tid][k] = (int)(s8[k] & 0x7FFu);
  }
  __syncthreads();

  // ---- Phase D: exact fp64 re-score of 8 candidates per row
  {
    int rr = tid >> 3, j = tid & 7;
    int code = top8i[rr][j];
    const float4* wr4 = (const float4*)(W + (size_t)code * DIM);
    const float*  xr  = x + (size_t)b * DIM * 256 + t0 + rr;
    double d0 = 0.0, d1 = 0.0, d2 = 0.0, d3 = 0.0;
    for (int d4 = 0; d4 < 128; ++d4) {
      float4 wv = wr4[d4];
      float xa = xr[(size_t)(d4*4 + 0) * 256];
      float xb = xr[(size_t)(d4*4 + 1) * 256];
      float xc = xr[(size_t)(d4*4 + 2) * 256];
      float xd = xr[(size_t)(d4*4 + 3) * 256];
      d0 = fma((double)xa, (double)wv.x, d0);
      d1 = fma((double)xb, (double)wv.y, d1);
      d2 = fma((double)xc, (double)wv.z, d2);
      d3 = fma((double)xd, (double)wv.w, d3);
    }
    sc8[rr][j] = w2d[code] - 2.0 * ((d0 + d1) + (d2 + d3));
  }
  __syncthreads();

  // ---- final order: sort 8 by (score, index) asc == top_k(-dist) order
  if (tid < MB) {
    double sd[8]; int id_[8];
    #pragma unroll
    for (int k = 0; k < 8; ++k) { sd[k] = sc8[tid][k]; id_[k] = top8i[tid][k]; }
    #pragma unroll
    for (int i = 0; i < 7; ++i)
      #pragma unroll
      for (int jj = 0; jj < 7; ++jj)
        if (jj < 7 - i) {
          bool sw = (sd[jj] > sd[jj+1]) ||
                    (sd[jj] == sd[jj+1] && id_[jj] > id_[jj+1]);
          if (sw) {
            double td = sd[jj]; sd[jj] = sd[jj+1]; sd[jj+1] = td;
            int    tt = id_[jj]; id_[jj] = id_[jj+1]; id_[jj+1] = tt;
          }
        }
    int n = n0 + tid;
    idx3s[tid] = make_int4(id_[0], id_[1], id_[2], 0);
    out[OUT_IDX_OFF + n] = (float)id_[2];
    atomicAdd(&counts[id_[0]], 1);
    atomicAdd(&counts[id_[1]], 1);
    atomicAdd(&counts[id_[2]], 1);
  }
  __syncthreads();

  // ---- Phase E: fused quantize + straight-through + loss
  {
    int rr = tid & 31, g = tid >> 5;       // 8 d-groups of 64 dims
    int4 ii = idx3s[rr];
    const float4* w0 = (const float4*)(W + (size_t)ii.x * DIM);
    const float4* w1 = (const float4*)(W + (size_t)ii.y * DIM);
    const float4* w2 = (const float4*)(W + (size_t)ii.z * DIM);
    const float*  xr = x + (size_t)b * DIM * 256 + t0 + rr;
    float* outq = out + OUT_Q_OFF + (size_t)b * DIM * 256 + t0 + rr;
    float lsum = 0.0f;
    #pragma unroll 4
    for (int d4 = 0; d4 < 16; ++d4) {
      int idx4 = g * 16 + d4;
      float4 a0 = w0[idx4], a1 = w1[idx4], a2 = w2[idx4];
      float qv[4] = { (a0.x + a1.x + a2.x) * (1.0f/3.0f),
                      (a0.y + a1.y + a2.y) * (1.0f/3.0f),
                      (a0.z + a1.z + a2.z) * (1.0f/3.0f),
                      (a0.w + a1.w + a2.w) * (1.0f/3.0f) };
      #pragma unroll
      for (int e = 0; e < 4; ++e) {
        size_t off = (size_t)(idx4 * 4 + e) * 256;
        float xv = xr[off];
        float diff = qv[e] - xv;             // quantized - inp
        outq[off] = xv + diff;               // straight-through value
        lsum += diff * diff;
      }
    }
    for (int o = 32; o > 0; o >>= 1) lsum += __shfl_down(lsum, o);
    if (lane == 0) lred[w] = lsum;
  }
  __syncthreads();
  if (tid == 0)
    atomicAdd(loss_acc, (lred[0] + lred[1]) + (lred[2] + lred[3]));
}

// ---------------- k_final: loss + perplexity
__global__ __launch_bounds__(256) void k_final(
    const int* __restrict__ counts, const float* __restrict__ loss_acc,
    float* __restrict__ out)
{
  int tid = threadIdx.x;
  float ent = 0.0f;
  for (int k = tid; k < KC; k += 256) {
    float p = (float)counts[k] * (1.0f / 16384.0f);
    ent += p * logf(p + 1e-10f);
  }
  for (int o = 32; o > 0; o >>= 1) ent += __shfl_down(ent, o);
  __shared__ float ps[4];
  if ((tid & 63) == 0) ps[tid >> 6] = ent;
  __syncthreads();
  if (tid == 0) {
    float total = (ps[0] + ps[1]) + (ps[2] + ps[3]);
    out[0] = 1.25f * loss_acc[0] * (1.0f / 8388608.0f);  // q + 0.25*e latent
    out[OUT_P_OFF] = expf(-total);
  }
}

extern "C" void kernel_launch(void* const* d_in, const int* in_sizes, int n_in,
                              void* d_out, int out_size, void* d_ws, size_t ws_size,
                              hipStream_t stream) {
  const float* x = (const float*)d_in[0];
  const float* W = (const float*)d_in[1];
  float* out = (float*)d_out;
  char* ws = (char*)d_ws;
  int*           counts   = (int*)(ws + WS_COUNTS);
  float*         loss_acc = (float*)(ws + WS_LOSS);
  double*        w2d      = (double*)(ws + WS_W2D);
  float*         w2f      = (float*)(ws + WS_W2F);
  unsigned char* Wb       = (unsigned char*)(ws + WS_WB);

  hipMemsetAsync(ws, 0, 8448, stream);   // counts + loss accumulator
  k_w2<<<KC / 4, 256, 0, stream>>>(W, w2d, w2f);
  k_reorder<<<512, 256, 0, stream>>>(W, Wb);
  k_main<<<NROWS / MB, 256, 0, stream>>>(x, W, Wb, w2f, w2d, counts, out, loss_acc);
  k_final<<<1, 256, 0, stream>>>(counts, loss_acc, out);
}